// Round 1
// baseline (996.109 us; speedup 1.0000x reference)
//
#include <hip/hip_runtime.h>
#include <hip/hip_bf16.h>
#include <cstdint>
#include <cstddef>

// Problem dims
constexpr int BROWS   = 16384;
constexpr int OBJ_FEAT = 1024;
constexpr int PPF_DIM  = 64;
constexpr int HIDDEN   = 512;
constexpr int OBJ_NUM  = 1001;
constexpr int PRED_NUM = 132;
constexpr int OBJ_PAD  = 1024;  // 1001 -> 1024
constexpr int PRED_PAD = 256;   // 132  -> 256
constexpr int PF_K     = HIDDEN + PPF_DIM;  // 576

typedef __attribute__((ext_vector_type(8))) short bf16x8;
typedef __attribute__((ext_vector_type(4))) float f32x4;

static __device__ __forceinline__ unsigned short f2bf(float f) {
  // round-to-nearest-even fp32 -> bf16 (inputs finite; no NaN handling needed)
  unsigned int u = __float_as_uint(f);
  u += 0x7fffu + ((u >> 16) & 1u);
  return (unsigned short)(u >> 16);
}

// ---------------- cast kernels ----------------

// fp32 -> bf16, vectorized x4
__global__ void cast_f32_bf16_vec(const float4* __restrict__ in,
                                  ushort4* __restrict__ out, int n4) {
  int i = blockIdx.x * 256 + threadIdx.x;
  if (i < n4) {
    float4 v = in[i];
    ushort4 o;
    o.x = f2bf(v.x); o.y = f2bf(v.y); o.z = f2bf(v.z); o.w = f2bf(v.w);
    out[i] = o;
  }
}

// W [K,N] fp32 row-major -> Wt [Npad,K] bf16 (zero-padded rows n>=N)
// grid: (ceil(K/256), Npad); coalesced writes, L2 absorbs strided reads (small W)
__global__ void cast_transpose(const float* __restrict__ W,
                               unsigned short* __restrict__ Wt,
                               int K, int N) {
  int k = blockIdx.x * 256 + threadIdx.x;
  int n = blockIdx.y;
  if (k < K) {
    float v = (n < N) ? W[(size_t)k * N + n] : 0.0f;
    Wt[(size_t)n * K + k] = f2bf(v);
  }
}

// ppf [B,64] fp32 -> Apf[:, 512:576] bf16 (Apf leading dim 576)
__global__ void cast_ppf(const float* __restrict__ ppf,
                         unsigned short* __restrict__ Apf) {
  int idx = blockIdx.x * 256 + threadIdx.x;  // BROWS*64 total
  int row = idx >> 6, c = idx & 63;
  Apf[(size_t)row * PF_K + HIDDEN + c] = f2bf(ppf[idx]);
}

// ---------------- GEMM ----------------
// C[M,N] = A[M,K] * Bt[N,K]^T   (A,Bt bf16, acc fp32)
// 128x128 block tile, BK=32, 256 threads = 4 waves (2x2), each wave 64x64 via
// 4x4 grid of 16x16x32 MFMA. global_load_lds width-16 staging (m97 structure).
// MODE 0: out bf16 = relu(acc + bias[n]), leading dim ldout
// MODE 1: out fp32 = acc
// MODE 2: out fp32 = acc + so2p[gts[m]*1001+gto[m]][n] * exp(factor)
template <int MODE>
__global__ __launch_bounds__(256)
void gemm_bt(const unsigned short* __restrict__ A,
             const unsigned short* __restrict__ Bt,
             int K,
             float* __restrict__ outF,
             unsigned short* __restrict__ outB,
             int ldout, int Nreal,
             const float* __restrict__ bias,
             const int* __restrict__ gts, const int* __restrict__ gto,
             const float* __restrict__ so2p, const float* __restrict__ factor) {
  __shared__ unsigned short sA[128 * 32];
  __shared__ unsigned short sB[128 * 32];

  const int tid  = threadIdx.x;
  const int lane = tid & 63;
  const int wave = tid >> 6;
  const int wm   = wave >> 1;   // 0..1
  const int wn   = wave & 1;    // 0..1
  const int quad = lane >> 4;   // 0..3
  const int r16  = lane & 15;

  const int m0 = blockIdx.y * 128;
  const int n0 = blockIdx.x * 128;

  f32x4 acc[4][4] = {};

  for (int k0 = 0; k0 < K; k0 += 32) {
    __syncthreads();  // previous iter's LDS reads done before overwrite
#pragma unroll
    for (int j = 0; j < 2; ++j) {
      int chunk = tid + j * 256;       // 0..511, 16B each
      int row = chunk >> 2;            // 0..127
      int c8  = chunk & 3;             // which 8-elem group in the 32-wide row
      const unsigned short* ga = A + (size_t)(m0 + row) * K + k0 + c8 * 8;
      __builtin_amdgcn_global_load_lds(
          (const __attribute__((address_space(1))) void*)ga,
          (__attribute__((address_space(3))) void*)(sA + chunk * 8), 16, 0, 0);
      const unsigned short* gb = Bt + (size_t)(n0 + row) * K + k0 + c8 * 8;
      __builtin_amdgcn_global_load_lds(
          (const __attribute__((address_space(1))) void*)gb,
          (__attribute__((address_space(3))) void*)(sB + chunk * 8), 16, 0, 0);
    }
    __syncthreads();  // drains vmcnt(0): staged data visible

    bf16x8 af[4], bfr[4];
#pragma unroll
    for (int i = 0; i < 4; ++i)
      af[i] = *reinterpret_cast<const bf16x8*>(sA + (wm * 64 + i * 16 + r16) * 32 + quad * 8);
#pragma unroll
    for (int j = 0; j < 4; ++j)
      bfr[j] = *reinterpret_cast<const bf16x8*>(sB + (wn * 64 + j * 16 + r16) * 32 + quad * 8);
#pragma unroll
    for (int i = 0; i < 4; ++i)
#pragma unroll
      for (int j = 0; j < 4; ++j)
        acc[i][j] = __builtin_amdgcn_mfma_f32_16x16x32_bf16(af[i], bfr[j], acc[i][j], 0, 0, 0);
  }

  float ef = 0.0f;
  if (MODE == 2) ef = expf(factor[0]);

#pragma unroll
  for (int i = 0; i < 4; ++i) {
    int mbase = m0 + wm * 64 + i * 16 + quad * 4;
#pragma unroll
    for (int j = 0; j < 4; ++j) {
      int n = n0 + wn * 64 + j * 16 + r16;
      if (n < Nreal) {
#pragma unroll
        for (int reg = 0; reg < 4; ++reg) {
          int m = mbase + reg;
          float v = acc[i][j][reg];
          if (MODE == 0) {
            v = fmaxf(v + bias[n], 0.0f);
            outB[(size_t)m * ldout + n] = f2bf(v);
          } else if (MODE == 1) {
            outF[(size_t)m * ldout + n] = v;
          } else {
            long rowidx = (long)gts[m] * OBJ_NUM + gto[m];
            v += so2p[rowidx * PRED_NUM + n] * ef;
            outF[(size_t)m * ldout + n] = v;
          }
        }
      }
    }
  }
}

// ---------------- launch ----------------

extern "C" void kernel_launch(void* const* d_in, const int* in_sizes, int n_in,
                              void* d_out, int out_size, void* d_ws, size_t ws_size,
                              hipStream_t stream) {
  const float* inp_sf  = (const float*)d_in[0];
  const float* inp_of  = (const float*)d_in[1];
  const float* inp_ppf = (const float*)d_in[2];
  const float* inp_pvf = (const float*)d_in[3];
  const int*   gt_s    = (const int*)d_in[4];
  const int*   gt_o    = (const int*)d_in[5];
  const float* W_obj1  = (const float*)d_in[6];
  const float* b_obj1  = (const float*)d_in[7];
  const float* W_obj2  = (const float*)d_in[8];
  const float* W_pvf   = (const float*)d_in[9];
  const float* b_pvf   = (const float*)d_in[10];
  const float* W_pf    = (const float*)d_in[11];
  const float* b_pf    = (const float*)d_in[12];
  const float* W_pred  = (const float*)d_in[13];
  const float* so2p    = (const float*)d_in[14];
  const float* so2p_f  = (const float*)d_in[15];

  float* out_s = (float*)d_out;
  float* out_o = out_s + (size_t)BROWS * OBJ_NUM;
  float* out_p = out_o + (size_t)BROWS * OBJ_NUM;

  // workspace layout (~73 MB; A/H buffers reused across the three paths)
  char* ws = (char*)d_ws;
  unsigned short* A_buf = (unsigned short*)ws; ws += (size_t)BROWS * 1024 * 2;  // 32 MB
  unsigned short* H_buf = (unsigned short*)ws; ws += (size_t)BROWS * 512 * 2;   // 16 MB
  unsigned short* Apf   = (unsigned short*)ws; ws += (size_t)BROWS * PF_K * 2;  // 18 MB
  unsigned short* Wt_obj1 = (unsigned short*)ws; ws += (size_t)HIDDEN * OBJ_FEAT * 2;
  unsigned short* Wt_obj2 = (unsigned short*)ws; ws += (size_t)OBJ_PAD * HIDDEN * 2;
  unsigned short* Wt_pvf  = (unsigned short*)ws; ws += (size_t)HIDDEN * OBJ_FEAT * 2;
  unsigned short* Wt_pf   = (unsigned short*)ws; ws += (size_t)HIDDEN * PF_K * 2;
  unsigned short* Wt_pred = (unsigned short*)ws; ws += (size_t)PRED_PAD * HIDDEN * 2;

  // --- weight casts (transposed, zero-padded) ---
  cast_transpose<<<dim3((OBJ_FEAT + 255) / 256, HIDDEN), 256, 0, stream>>>(W_obj1, Wt_obj1, OBJ_FEAT, HIDDEN);
  cast_transpose<<<dim3((HIDDEN + 255) / 256, OBJ_PAD), 256, 0, stream>>>(W_obj2, Wt_obj2, HIDDEN, OBJ_NUM);
  cast_transpose<<<dim3((OBJ_FEAT + 255) / 256, HIDDEN), 256, 0, stream>>>(W_pvf, Wt_pvf, OBJ_FEAT, HIDDEN);
  cast_transpose<<<dim3((PF_K + 255) / 256, HIDDEN), 256, 0, stream>>>(W_pf, Wt_pf, PF_K, HIDDEN);
  cast_transpose<<<dim3((HIDDEN + 255) / 256, PRED_PAD), 256, 0, stream>>>(W_pred, Wt_pred, HIDDEN, PRED_NUM);

  const int n4_big = BROWS * 1024 / 4;   // activations cast, x4 vectorized
  const dim3 cgrid((n4_big + 255) / 256);

  // --- subject path ---
  cast_f32_bf16_vec<<<cgrid, 256, 0, stream>>>((const float4*)inp_sf, (ushort4*)A_buf, n4_big);
  gemm_bt<0><<<dim3(HIDDEN / 128, BROWS / 128), 256, 0, stream>>>(
      A_buf, Wt_obj1, OBJ_FEAT, nullptr, H_buf, HIDDEN, HIDDEN, b_obj1, nullptr, nullptr, nullptr, nullptr);
  gemm_bt<1><<<dim3(OBJ_PAD / 128, BROWS / 128), 256, 0, stream>>>(
      H_buf, Wt_obj2, HIDDEN, out_s, nullptr, OBJ_NUM, OBJ_NUM, nullptr, nullptr, nullptr, nullptr, nullptr);

  // --- object path (reuse A_buf / H_buf; stream serializes) ---
  cast_f32_bf16_vec<<<cgrid, 256, 0, stream>>>((const float4*)inp_of, (ushort4*)A_buf, n4_big);
  gemm_bt<0><<<dim3(HIDDEN / 128, BROWS / 128), 256, 0, stream>>>(
      A_buf, Wt_obj1, OBJ_FEAT, nullptr, H_buf, HIDDEN, HIDDEN, b_obj1, nullptr, nullptr, nullptr, nullptr);
  gemm_bt<1><<<dim3(OBJ_PAD / 128, BROWS / 128), 256, 0, stream>>>(
      H_buf, Wt_obj2, HIDDEN, out_o, nullptr, OBJ_NUM, OBJ_NUM, nullptr, nullptr, nullptr, nullptr, nullptr);

  // --- predicate path ---
  cast_f32_bf16_vec<<<cgrid, 256, 0, stream>>>((const float4*)inp_pvf, (ushort4*)A_buf, n4_big);
  cast_ppf<<<dim3(BROWS * PPF_DIM / 256), 256, 0, stream>>>(inp_ppf, Apf);
  // pvf_emb -> Apf[:, 0:512] (ldout = 576)
  gemm_bt<0><<<dim3(HIDDEN / 128, BROWS / 128), 256, 0, stream>>>(
      A_buf, Wt_pvf, OBJ_FEAT, nullptr, Apf, PF_K, HIDDEN, b_pvf, nullptr, nullptr, nullptr, nullptr);
  // pf_emb = relu(Apf @ W_pf + b_pf) -> H_buf
  gemm_bt<0><<<dim3(HIDDEN / 128, BROWS / 128), 256, 0, stream>>>(
      Apf, Wt_pf, PF_K, nullptr, H_buf, HIDDEN, HIDDEN, b_pf, nullptr, nullptr, nullptr, nullptr);
  // p_score + so2p gather
  gemm_bt<2><<<dim3(PRED_PAD / 128, BROWS / 128), 256, 0, stream>>>(
      H_buf, Wt_pred, HIDDEN, out_p, nullptr, PRED_NUM, PRED_NUM, nullptr, gt_s, gt_o, so2p, so2p_f);

  (void)in_sizes; (void)n_in; (void)out_size; (void)ws_size;
}

// Round 2
// 996.109 us; speedup vs baseline: 1.0000x; 1.0000x over previous
//
#include <hip/hip_runtime.h>
#include <hip/hip_bf16.h>
#include <cstdint>
#include <cstddef>

constexpr int BROWS   = 16384;
constexpr int OBJ_FEAT = 1024;
constexpr int PPF_DIM  = 64;
constexpr int HIDDEN   = 512;
constexpr int OBJ_NUM  = 1001;
constexpr int PRED_NUM = 132;
constexpr int OBJ_PAD  = 1024;
constexpr int PRED_PAD = 256;
constexpr int PF_K     = HIDDEN + PPF_DIM;  // 576

typedef __attribute__((ext_vector_type(8))) short bf16x8;
typedef __attribute__((ext_vector_type(4))) float f32x4;

static __device__ __forceinline__ unsigned short f2bf(float f) {
  unsigned int u = __float_as_uint(f);
  u += 0x7fffu + ((u >> 16) & 1u);
  return (unsigned short)(u >> 16);
}

// All 5 weight transposes in one dispatch. W [K,N] fp32 -> Wt [Npad,K] bf16,
// zero-padded for n >= N. Branch on blockIdx.z (block-uniform).
__global__ void cast_w_all(const float* __restrict__ W0, const float* __restrict__ W1,
                           const float* __restrict__ W2, const float* __restrict__ W3,
                           const float* __restrict__ W4,
                           unsigned short* __restrict__ T0, unsigned short* __restrict__ T1,
                           unsigned short* __restrict__ T2, unsigned short* __restrict__ T3,
                           unsigned short* __restrict__ T4) {
  const int z = blockIdx.z;
  const float* W; unsigned short* T; int K, N, Npad;
  if      (z == 0) { W = W0; T = T0; K = 1024; N = 512;  Npad = 512;  }
  else if (z == 1) { W = W1; T = T1; K = 512;  N = 1001; Npad = 1024; }
  else if (z == 2) { W = W2; T = T2; K = 1024; N = 512;  Npad = 512;  }
  else if (z == 3) { W = W3; T = T3; K = 576;  N = 512;  Npad = 512;  }
  else             { W = W4; T = T4; K = 512;  N = 132;  Npad = 256;  }
  int n = blockIdx.y;
  int k = blockIdx.x * 256 + threadIdx.x;
  if (n >= Npad || k >= K) return;
  float v = (n < N) ? W[(size_t)k * N + n] : 0.0f;
  T[(size_t)n * K + k] = f2bf(v);
}

// ---------------- fused GEMM ----------------
// C[M,N] = A[M,K] * Bt[N,K]^T, 128x128 tile, BK=32, 4 waves (2x2), 4x4 MFMA
// 16x16x32 per wave (m97 structure).
// A source is K-split:
//   k in [0, K1):  bf16, Ab (ld ldAb), staged via global_load_lds width-16
//   k in [K1, K):  fp32, row-split (m < M1f -> Af0 else Af1, ld ldAf),
//                  loaded as float4 into regs (prefetched during MFMA phase),
//                  converted to bf16, ds_write-staged.
// MODE 0: outB bf16 = relu(acc + bias[n])
// MODE 1: outF fp32 = acc
// MODE 2: outF fp32 = acc + so2p[gts[m]*OBJ_NUM+gto[m]][n] * exp(factor)
template <int MODE>
__global__ __launch_bounds__(256)
void gemm_fused(const unsigned short* __restrict__ Ab, int ldAb, int K1,
                const float* __restrict__ Af0, const float* __restrict__ Af1,
                int M1f, int ldAf,
                const unsigned short* __restrict__ Bt, int K,
                float* __restrict__ outF, unsigned short* __restrict__ outB,
                int ldout, int Nreal,
                const float* __restrict__ bias,
                const int* __restrict__ gts, const int* __restrict__ gto,
                const float* __restrict__ so2p, const float* __restrict__ factor) {
  __shared__ unsigned short sA[128 * 32];
  __shared__ unsigned short sB[128 * 32];

  const int tid  = threadIdx.x;
  const int lane = tid & 63;
  const int wave = tid >> 6;
  const int wm   = wave >> 1;
  const int wn   = wave & 1;
  const int quad = lane >> 4;
  const int r16  = lane & 15;
  const int m0   = blockIdx.y * 128;
  const int n0   = blockIdx.x * 128;

  // block-uniform fp32 A base (128-row tiles never straddle M1f: both are x128)
  const float* afb = nullptr;
  if (K1 < K)
    afb = (m0 < M1f) ? (Af0 + (size_t)m0 * ldAf)
                     : (Af1 + (size_t)(m0 - M1f) * ldAf);

  float4 pa[4];
  auto loadA = [&](int k0) {
    const int kf = k0 - K1;
#pragma unroll
    for (int j = 0; j < 4; ++j) {
      int ch = tid + j * 256, row = ch >> 3, c4 = (ch & 7) * 4;
      pa[j] = *reinterpret_cast<const float4*>(afb + (size_t)row * ldAf + kf + c4);
    }
  };
  if (K1 == 0 && K1 < K) loadA(0);  // K1>0 cases prefetch at iter K1-32

  f32x4 acc[4][4] = {};

  for (int k0 = 0; k0 < K; k0 += 32) {
    __syncthreads();  // previous iter's LDS reads done
    if (k0 < K1) {
#pragma unroll
      for (int j = 0; j < 2; ++j) {
        int ch = tid + j * 256, row = ch >> 2, c8 = ch & 3;
        const unsigned short* ga = Ab + (size_t)(m0 + row) * ldAb + k0 + c8 * 8;
        __builtin_amdgcn_global_load_lds(
            (const __attribute__((address_space(1))) void*)ga,
            (__attribute__((address_space(3))) void*)(sA + ch * 8), 16, 0, 0);
      }
    } else {
      // consume prefetched fp32 tile: convert + stage
#pragma unroll
      for (int j = 0; j < 4; ++j) {
        int ch = tid + j * 256, row = ch >> 3, c4 = (ch & 7) * 4;
        ushort4 o;
        o.x = f2bf(pa[j].x); o.y = f2bf(pa[j].y);
        o.z = f2bf(pa[j].z); o.w = f2bf(pa[j].w);
        *reinterpret_cast<ushort4*>(sA + row * 32 + c4) = o;
      }
    }
#pragma unroll
    for (int j = 0; j < 2; ++j) {
      int ch = tid + j * 256, row = ch >> 2, c8 = ch & 3;
      const unsigned short* gb = Bt + (size_t)(n0 + row) * K + k0 + c8 * 8;
      __builtin_amdgcn_global_load_lds(
          (const __attribute__((address_space(1))) void*)gb,
          (__attribute__((address_space(3))) void*)(sB + ch * 8), 16, 0, 0);
    }
    __syncthreads();  // staging visible

    // prefetch next fp32 A tile into regs — latency hides behind MFMA phase
    int kn = k0 + 32;
    if (kn >= K1 && kn < K) loadA(kn);

    bf16x8 af[4], bfr[4];
#pragma unroll
    for (int i = 0; i < 4; ++i)
      af[i] = *reinterpret_cast<const bf16x8*>(sA + (wm * 64 + i * 16 + r16) * 32 + quad * 8);
#pragma unroll
    for (int j = 0; j < 4; ++j)
      bfr[j] = *reinterpret_cast<const bf16x8*>(sB + (wn * 64 + j * 16 + r16) * 32 + quad * 8);
#pragma unroll
    for (int i = 0; i < 4; ++i)
#pragma unroll
      for (int j = 0; j < 4; ++j)
        acc[i][j] = __builtin_amdgcn_mfma_f32_16x16x32_bf16(af[i], bfr[j], acc[i][j], 0, 0, 0);
  }

  float ef = 0.0f;
  if (MODE == 2) ef = expf(factor[0]);

#pragma unroll
  for (int i = 0; i < 4; ++i) {
    int mbase = m0 + wm * 64 + i * 16 + quad * 4;
#pragma unroll
    for (int j = 0; j < 4; ++j) {
      int n = n0 + wn * 64 + j * 16 + r16;
      if (n < Nreal) {
#pragma unroll
        for (int reg = 0; reg < 4; ++reg) {
          int m = mbase + reg;
          float v = acc[i][j][reg];
          if (MODE == 0) {
            v = fmaxf(v + bias[n], 0.0f);
            outB[(size_t)m * ldout + n] = f2bf(v);
          } else if (MODE == 1) {
            outF[(size_t)m * ldout + n] = v;
          } else {
            long rowidx = (long)gts[m] * OBJ_NUM + gto[m];
            v += so2p[rowidx * PRED_NUM + n] * ef;
            outF[(size_t)m * ldout + n] = v;
          }
        }
      }
    }
  }
}

// ---------------- launch ----------------

extern "C" void kernel_launch(void* const* d_in, const int* in_sizes, int n_in,
                              void* d_out, int out_size, void* d_ws, size_t ws_size,
                              hipStream_t stream) {
  const float* inp_sf  = (const float*)d_in[0];
  const float* inp_of  = (const float*)d_in[1];
  const float* inp_ppf = (const float*)d_in[2];
  const float* inp_pvf = (const float*)d_in[3];
  const int*   gt_s    = (const int*)d_in[4];
  const int*   gt_o    = (const int*)d_in[5];
  const float* W_obj1  = (const float*)d_in[6];
  const float* b_obj1  = (const float*)d_in[7];
  const float* W_obj2  = (const float*)d_in[8];
  const float* W_pvf   = (const float*)d_in[9];
  const float* b_pvf   = (const float*)d_in[10];
  const float* W_pf    = (const float*)d_in[11];
  const float* b_pf    = (const float*)d_in[12];
  const float* W_pred  = (const float*)d_in[13];
  const float* so2p    = (const float*)d_in[14];
  const float* so2p_f  = (const float*)d_in[15];

  float* out_s = (float*)d_out;                         // [16384,1001]
  float* out_p = out_s + 2 * (size_t)BROWS * OBJ_NUM;   // [16384,132]
  // out_o immediately follows out_s: combined M=32768 GEMM writes both.

  char* ws = (char*)d_ws;
  unsigned short* H_buf = (unsigned short*)ws; ws += (size_t)2 * BROWS * HIDDEN * 2;  // 32 MB
  unsigned short* H2    = (unsigned short*)ws; ws += (size_t)BROWS * HIDDEN * 2;      // 16 MB
  unsigned short* Wt_obj1 = (unsigned short*)ws; ws += (size_t)HIDDEN * OBJ_FEAT * 2;
  unsigned short* Wt_obj2 = (unsigned short*)ws; ws += (size_t)OBJ_PAD * HIDDEN * 2;
  unsigned short* Wt_pvf  = (unsigned short*)ws; ws += (size_t)HIDDEN * OBJ_FEAT * 2;
  unsigned short* Wt_pf   = (unsigned short*)ws; ws += (size_t)HIDDEN * PF_K * 2;
  unsigned short* Wt_pred = (unsigned short*)ws; ws += (size_t)PRED_PAD * HIDDEN * 2;

  // 1) all weight casts
  cast_w_all<<<dim3(4, 1024, 5), 256, 0, stream>>>(
      W_obj1, W_obj2, W_pvf, W_pf, W_pred,
      Wt_obj1, Wt_obj2, Wt_pvf, Wt_pf, Wt_pred);

  // 2) s+o hidden: [32768,1024] fp32 (sf|of) x W_obj1 -> H_buf bf16 relu
  gemm_fused<0><<<dim3(HIDDEN / 128, 2 * BROWS / 128), 256, 0, stream>>>(
      nullptr, 0, 0, inp_sf, inp_of, BROWS, OBJ_FEAT,
      Wt_obj1, OBJ_FEAT, nullptr, H_buf, HIDDEN, HIDDEN, b_obj1,
      nullptr, nullptr, nullptr, nullptr);

  // 3) s+o scores: [32768,512] bf16 x W_obj2 -> out_s|out_o fp32
  gemm_fused<1><<<dim3(OBJ_PAD / 128, 2 * BROWS / 128), 256, 0, stream>>>(
      H_buf, HIDDEN, HIDDEN, nullptr, nullptr, 0, 0,
      Wt_obj2, HIDDEN, out_s, nullptr, OBJ_NUM, OBJ_NUM, nullptr,
      nullptr, nullptr, nullptr, nullptr);

  // 4) pvf_emb: [16384,1024] fp32 x W_pvf -> H_buf bf16 relu (reuse, ld 512)
  gemm_fused<0><<<dim3(HIDDEN / 128, BROWS / 128), 256, 0, stream>>>(
      nullptr, 0, 0, inp_pvf, inp_pvf, 1 << 30, OBJ_FEAT,
      Wt_pvf, OBJ_FEAT, nullptr, H_buf, HIDDEN, HIDDEN, b_pvf,
      nullptr, nullptr, nullptr, nullptr);

  // 5) pf_emb: A = [H_buf bf16 (k<512) | ppf fp32 (k>=512)] x W_pf -> H2 relu
  gemm_fused<0><<<dim3(HIDDEN / 128, BROWS / 128), 256, 0, stream>>>(
      H_buf, HIDDEN, HIDDEN, inp_ppf, inp_ppf, 1 << 30, PPF_DIM,
      Wt_pf, PF_K, nullptr, H2, HIDDEN, HIDDEN, b_pf,
      nullptr, nullptr, nullptr, nullptr);

  // 6) p_score + knowledge gather
  gemm_fused<2><<<dim3(PRED_PAD / 128, BROWS / 128), 256, 0, stream>>>(
      H2, HIDDEN, HIDDEN, nullptr, nullptr, 0, 0,
      Wt_pred, HIDDEN, out_p, nullptr, PRED_NUM, PRED_NUM, nullptr,
      gt_s, gt_o, so2p, so2p_f);

  (void)in_sizes; (void)n_in; (void)out_size; (void)ws_size;
}